// Round 3
// baseline (90.657 us; speedup 1.0000x reference)
//
#include <hip/hip_runtime.h>

// Problem constants (match reference)
#define B_ 16
#define F_ 256
#define N_ 16384
#define L_ 4096
#define K_ 9

#define NTHR 1024
#define NBLK 256            // 1 block/CU (LDS-limited); persistent
#define NPAIR (B_ * F_ / 2) // 2048 row pairs
#define PAIRS_PER_BLK (NPAIR / NBLK) // 8

// ---------------------------------------------------------------------------
// Persistent pair kernel.
//  - pairbuf[n] = {rowA[n], rowB[n]} interleaved in LDS (128 KiB + sentinel)
//    -> one ds_read_b64 gathers both rows for an index.
//  - Each thread pre-decodes its 36 (idx,mask) entries into 18 packed VGPRs
//    (sentinel N_ for masked entries; pairbuf[N_] = {0,0}).
//  - Pipeline: while computing pair p from LDS, global loads for pair p+1
//    sit in flight into registers; they are written to LDS only after the
//    barrier that retires pair p's reads. HBM stream stays continuous.
// ---------------------------------------------------------------------------
__global__ __launch_bounds__(NTHR, 4) void pool_pair_kernel(
    const float* __restrict__ img, const int* __restrict__ idx,
    const float* __restrict__ mask, float* __restrict__ out) {
  __shared__ __align__(16) float2 pairbuf[N_ + 2]; // sentinel at [N_]
  const int tid = threadIdx.x;
  const int bid = blockIdx.x;

  // ---- decode this thread's 36 indices (l = it*NTHR+tid, it<4, k<9) ----
  unsigned cpk[18];
#pragma unroll
  for (int j = 0; j < 18; ++j) {
    const int s0 = 2 * j, s1 = 2 * j + 1; // flat slots it*9+k
    const int it0 = s0 / K_, k0 = s0 % K_;
    const int it1 = s1 / K_, k1 = s1 % K_;
    int t0 = (it0 * NTHR + tid) * K_ + k0;
    int t1 = (it1 * NTHR + tid) * K_ + k1;
    unsigned id0 = (mask[t0] != 0.0f) ? (unsigned)idx[t0] : (unsigned)N_;
    unsigned id1 = (mask[t1] != 0.0f) ? (unsigned)idx[t1] : (unsigned)N_;
    cpk[j] = id0 | (id1 << 16);
  }

  const float2* imgf2 = (const float2*)img; // 8192 float2 per row
  float2 sa[8], sb[8];                      // staging regs (32 VGPRs)

  // ---- prologue: load + write pair 0 ----
  {
    const int pid = bid * PAIRS_PER_BLK;
    const float2* A = imgf2 + (size_t)(2 * pid) * (N_ / 2);
    const float2* Bp = A + (N_ / 2);
#pragma unroll
    for (int i = 0; i < 8; ++i) {
      sa[i] = A[tid + i * NTHR];
      sb[i] = Bp[tid + i * NTHR];
    }
    if (tid == 0) pairbuf[N_] = make_float2(0.0f, 0.0f);
#pragma unroll
    for (int i = 0; i < 8; ++i) {
      int e = tid + i * NTHR;
      *(float4*)(&pairbuf[2 * e]) =
          make_float4(sa[i].x, sb[i].x, sa[i].y, sb[i].y);
    }
  }
  __syncthreads();

#pragma unroll 1
  for (int p = 0; p < PAIRS_PER_BLK; ++p) {
    const int pid = bid * PAIRS_PER_BLK + p;

    // issue next pair's loads early (hide HBM latency under compute)
    if (p + 1 < PAIRS_PER_BLK) {
      const float2* A = imgf2 + (size_t)(2 * (pid + 1)) * (N_ / 2);
      const float2* Bp = A + (N_ / 2);
#pragma unroll
      for (int i = 0; i < 8; ++i) {
        sa[i] = A[tid + i * NTHR];
        sb[i] = Bp[tid + i * NTHR];
      }
    }

    // compute pair p from LDS
    float* outA = out + (size_t)(2 * pid) * L_;
    float* outB = outA + L_;
#pragma unroll
    for (int it = 0; it < 4; ++it) {
      int l = it * NTHR + tid;
      float ma = -INFINITY, mb = -INFINITY;
#pragma unroll
      for (int k = 0; k < K_; ++k) {
        const int slot = it * K_ + k;
        unsigned w = cpk[slot >> 1];
        unsigned id = (slot & 1) ? (w >> 16) : (w & 0xffffu);
        float2 v = pairbuf[id]; // ds_read_b64: both rows at once
        ma = fmaxf(ma, v.x);
        mb = fmaxf(mb, v.y);
      }
      outA[l] = ma; // coalesced
      outB[l] = mb;
    }
    __syncthreads(); // all reads of pair p done

    if (p + 1 < PAIRS_PER_BLK) {
#pragma unroll
      for (int i = 0; i < 8; ++i) { // vmcnt wait auto-inserted
        int e = tid + i * NTHR;
        *(float4*)(&pairbuf[2 * e]) =
            make_float4(sa[i].x, sb[i].x, sa[i].y, sb[i].y);
      }
      __syncthreads(); // pair p+1 visible
    }
  }
}

extern "C" void kernel_launch(void* const* d_in, const int* in_sizes, int n_in,
                              void* d_out, int out_size, void* d_ws, size_t ws_size,
                              hipStream_t stream) {
  const float* img = (const float*)d_in[0];
  const int* idx = (const int*)d_in[1];
  const float* mask = (const float*)d_in[2];
  float* out = (float*)d_out;
  pool_pair_kernel<<<NBLK, NTHR, 0, stream>>>(img, idx, mask, out);
}